// Round 7
// baseline (547.616 us; speedup 1.0000x reference)
//
#include <hip/hip_runtime.h>
#include <hip/hip_bf16.h>
#include <cstdint>

// =================== BRUTE-FORCE PIPELINE, FP32 OUTPUT ===================
// Round-6 kernels verbatim; single change: d_out is float* (reference output
// dtype is float32 — the bf16 assumption was the 7-round bug).

// G1: kf[b,i,d] = sum_c k[b,c,i]*Wk[c,d] + bk[d].  grid 2 (b), block 512 (i)
__global__ __launch_bounds__(512) void g_kf(const float* __restrict__ k,
    const float* __restrict__ Wk, const float* __restrict__ bk,
    float* __restrict__ kf)
{
    int b = blockIdx.x;
    int i = threadIdx.x;
    const float* kb = k + (size_t)b * 131072;
    float acc[32];
    for (int d = 0; d < 32; ++d) acc[d] = bk[d];
    for (int c = 0; c < 256; ++c){
        float kv = kb[c*512 + i];
        for (int d = 0; d < 32; ++d) acc[d] += kv * Wk[c*32 + d];
    }
    float* dst = kf + (size_t)b*16384 + (size_t)i*32;
    for (int d = 0; d < 32; ++d) dst[d] = acc[d];
}

// G2: knorm[b,d] = sqrt(sum_i kf[b,i,d]^2).  grid 2 (b), block 32 (d)
__global__ __launch_bounds__(32) void g_knorm(const float* __restrict__ kf,
                                              float* __restrict__ knorm)
{
    int b = blockIdx.x, d = threadIdx.x;
    const float* src = kf + (size_t)b*16384;
    float s = 0.f;
    for (int i = 0; i < 512; ++i){ float v = src[i*32 + d]; s += v*v; }
    knorm[b*32 + d] = sqrtf(s);
}

// G3: qb[bg][j*32+d] = sum_c q[b,c,pos(g,j)]*Wq[c,d] + bq[d].  grid 128 (bg), block 512 (j)
__global__ __launch_bounds__(512) void g_qb(const float* __restrict__ q,
    const float* __restrict__ Wq, const float* __restrict__ bq,
    float* __restrict__ qb)
{
    int bg = blockIdx.x;
    int b = bg >> 6, g = bg & 63;
    int bh = g >> 4, bw = (g >> 2) & 3, bd = g & 3;
    int j = threadIdx.x;
    int ih = j >> 6, iw = (j >> 3) & 7, id = j & 7;
    int pos = (bh*8 + ih)*1024 + (bw*8 + iw)*32 + bd*8 + id;
    const float* qb_in = q + (size_t)b * 1048576 + pos;
    float qv[32];
    for (int c = 0; c < 32; ++c) qv[c] = qb_in[(size_t)c * 32768];
    float* dst = qb + (size_t)bg*16384 + (size_t)j*32;
    for (int d = 0; d < 32; ++d){
        float acc = bq[d];
        for (int c = 0; c < 32; ++c) acc += qv[c] * Wq[c*32 + d];
        dst[d] = acc;
    }
}

// G3b: qn2[bg*32+d] = sum_j qb^2.  grid 128 (bg), block 32 (d)
__global__ __launch_bounds__(32) void g_qn2(const float* __restrict__ qb,
                                            float* __restrict__ qn2)
{
    int bg = blockIdx.x, d = threadIdx.x;
    const float* src = qb + (size_t)bg*16384;
    float s = 0.f;
    for (int j = 0; j < 512; ++j){ float v = src[j*32 + d]; s += v*v; }
    qn2[bg*32 + d] = s;
}

// G3c: denom[bg] = sum_d knorm[b,d]*sqrt(qn2[bg,d]) + 1e-4.  grid 1, block 128 (bg)
__global__ __launch_bounds__(128) void g_denom(const float* __restrict__ knorm,
    const float* __restrict__ qn2, float* __restrict__ denomv)
{
    int bg = threadIdx.x;
    int b = bg >> 6;
    float s = 0.f;
    for (int d = 0; d < 32; ++d)
        s += knorm[b*32 + d] * sqrtf(qn2[bg*32 + d]);
    denomv[bg] = s + 1e-4f;
}

// G4: attention. grid 512 = (bg, j-quarter), block 128 (j within quarter).
__global__ __launch_bounds__(128) void g_attn(const float* __restrict__ kf,
    const float* __restrict__ qb, const float* __restrict__ denomv,
    float* __restrict__ oraw)
{
    int blk = blockIdx.x;
    int bg = blk >> 2, jq = blk & 3;
    int b = bg >> 6;
    int j = jq*128 + threadIdx.x;
    const float* kfb = kf + (size_t)b*16384;
    const float* qbs = qb + (size_t)bg*16384;
    float rden = 1.0f / denomv[bg];
    float qrow[32];
    for (int d = 0; d < 32; ++d) qrow[d] = qbs[j*32 + d];
    // pass 1: row max
    float m = -3e38f;
    for (int i = 0; i < 512; ++i){
        float s = 0.f;
        for (int d = 0; d < 32; ++d) s += kfb[i*32 + d] * qrow[d];
        s *= rden;
        m = fmaxf(m, s);
    }
    // pass 2: exp-sum + PV
    float S = 0.f;
    float acc[32];
    for (int c = 0; c < 32; ++c) acc[c] = 0.f;
    for (int i = 0; i < 512; ++i){
        float s = 0.f;
        for (int d = 0; d < 32; ++d) s += kfb[i*32 + d] * qrow[d];
        float e = expf(s*rden - m);
        S += e;
        const float* vrow = qbs + i*32;
        for (int c = 0; c < 32; ++c) acc[c] += e * vrow[c];
    }
    float rS = 1.0f / S;
    float* dst = oraw + (size_t)bg*16384 + (size_t)j*32;
    for (int c = 0; c < 32; ++c) dst[c] = acc[c] * rS;
}

// G5: per (bg,c): min-max over j, write vt[bg*16384 + c*512 + j]. grid 128, block 32 (c)
__global__ __launch_bounds__(32) void g_renorm(const float* __restrict__ oraw,
                                               float* __restrict__ vt)
{
    int bg = blockIdx.x, c = threadIdx.x;
    const float* src = oraw + (size_t)bg*16384;
    float mn = 3e38f, mx = -3e38f;
    for (int j = 0; j < 512; ++j){
        float v = src[j*32 + c];
        mn = fminf(mn, v); mx = fmaxf(mx, v);
    }
    float sc = 1.0f / (mx - mn + 1e-4f);
    float* dst = vt + (size_t)bg*16384 + (size_t)c*512;
    for (int j = 0; j < 512; ++j)
        dst[j] = (src[j*32 + c] - mn) * sc;
}

// G6: out[o] = bp[e] + sum_c vt[b*1M + f(p) + c] * Wp[c*32+e],  o = b*1M + e*32768 + p.
__global__ __launch_bounds__(256) void g_proj(const float* __restrict__ vt,
    const float* __restrict__ Wp, const float* __restrict__ bp,
    float* __restrict__ out)
{
    int o = blockIdx.x * 256 + threadIdx.x;     // [0, 2M)
    int b = o >> 20;
    int e = (o >> 15) & 31;
    int p = o & 32767;
    int h = p >> 10, w = (p >> 5) & 31, dsp = p & 31;
    int f = (h >> 3)*262144 + (w >> 3)*65536 + (dsp >> 3)*16384
          + (h & 7)*2048 + (w & 7)*256 + (dsp & 7)*32;
    const float* vrow = vt + (size_t)b*1048576 + f;
    float acc = bp[e];
    for (int c = 0; c < 32; ++c) acc += vrow[c] * Wp[c*32 + e];
    out[o] = acc;                               // fp32 output — the fix
}

extern "C" void kernel_launch(void* const* d_in, const int* in_sizes, int n_in,
                              void* d_out, int out_size, void* d_ws, size_t ws_size,
                              hipStream_t stream)
{
    const float* q  = (const float*)d_in[0];
    const float* k  = (const float*)d_in[1];
    const float* Wq = (const float*)d_in[2];
    const float* bq = (const float*)d_in[3];
    const float* Wk = (const float*)d_in[4];
    const float* bk = (const float*)d_in[5];
    const float* Wp = (const float*)d_in[6];
    const float* bp = (const float*)d_in[7];

    float* base   = (float*)d_ws;
    float* kf     = base;                       // 32768
    float* knorm  = base + 32768;               // 64
    float* qn2    = base + 32832;               // 4096
    float* denomv = base + 36928;               // 128
    float* qb     = base + 37056;               // 2,097,152
    float* oraw   = base + 2134208;             // 2,097,152
    float* vt     = qb;                         // alias: qb dead after g_attn
    float* outp   = (float*)d_out;

    hipLaunchKernelGGL(g_kf,     dim3(2),    dim3(512), 0, stream, k, Wk, bk, kf);
    hipLaunchKernelGGL(g_knorm,  dim3(2),    dim3(32),  0, stream, kf, knorm);
    hipLaunchKernelGGL(g_qb,     dim3(128),  dim3(512), 0, stream, q, Wq, bq, qb);
    hipLaunchKernelGGL(g_qn2,    dim3(128),  dim3(32),  0, stream, qb, qn2);
    hipLaunchKernelGGL(g_denom,  dim3(1),    dim3(128), 0, stream, knorm, qn2, denomv);
    hipLaunchKernelGGL(g_attn,   dim3(512),  dim3(128), 0, stream, kf, qb, denomv, oraw);
    hipLaunchKernelGGL(g_renorm, dim3(128),  dim3(32),  0, stream, oraw, vt);
    hipLaunchKernelGGL(g_proj,   dim3(8192), dim3(256), 0, stream, vt, Wp, bp, outp);
}